// Round 4
// baseline (2463.288 us; speedup 1.0000x reference)
//
#include <hip/hip_runtime.h>
#include <hip/hip_bf16.h>

#define B_ 2
#define S_ 1024
#define T_ (B_*S_)
#define D_ 2048
#define L_ 4
#define HQ_ 32
#define HKV_ 8
#define HD_ 64
#define I_ 5632
#define EPS_ 1e-5f
#define SCALE_ 0.125f

typedef __attribute__((ext_vector_type(4))) float  float4v;
typedef __attribute__((ext_vector_type(8))) short  short8v;

#define GLOAD16(g, l) \
  __builtin_amdgcn_global_load_lds((const __attribute__((address_space(1))) void*)(g), \
                                   (__attribute__((address_space(3))) void*)(l), 16, 0, 0)

__device__ __forceinline__ short f2bf(float f) {
  union { float f; unsigned u; } c; c.f = f;
  unsigned u = c.u + 0x7fffu + ((c.u >> 16) & 1u);
  return (short)(u >> 16);
}

// bijective XCD-aware block swizzle (m204); column-major decode so the
// row-tiles sharing one weight panel land on the same XCD's L2.
__device__ __forceinline__ void xcd_swizzle(int gx, int gy, int& bx, int& by) {
  int nwg = gx * gy;
  int orig = by * gx + bx;
  int q = nwg >> 3, r = nwg & 7;
  int xcd = orig & 7, loc = orig >> 3;
  int swz = (xcd < r ? xcd * (q + 1) : r * (q + 1) + (xcd - r) * q) + loc;
  bx = swz / gy;
  by = swz - bx * gy;
}

// ---------------- transpose f32 [K][N] -> bf16 [N][K] ----------------
__global__ __launch_bounds__(256)
void transpose_bf16(const float* __restrict__ in, short* __restrict__ out,
                    int K, int N) {
  __shared__ float t[32][33];
  const int bx = blockIdx.x * 32;
  const int by = blockIdx.y * 32;
  const int tx = threadIdx.x, ty = threadIdx.y;
  #pragma unroll
  for (int j = 0; j < 32; j += 8)
    t[ty + j][tx] = in[(size_t)(by + ty + j) * N + bx + tx];
  __syncthreads();
  #pragma unroll
  for (int j = 0; j < 32; j += 8)
    out[(size_t)(bx + ty + j) * K + by + tx] = f2bf(t[tx][ty + j]);
}

// ---------------- embedding gather ----------------
__global__ __launch_bounds__(256)
void embed_gather(const int* __restrict__ ids, const float* __restrict__ embed,
                  float* __restrict__ h) {
  size_t i = (size_t)blockIdx.x * 256 + threadIdx.x;
  int t  = (int)(i >> 9);
  int d4 = (int)(i & 511);
  ((float4v*)h)[i] = ((const float4v*)(embed + (size_t)ids[t] * D_))[d4];
}

// ---------------- fused residual-add + RMSNorm (bf16 or f32 out) ----------------
__global__ __launch_bounds__(256)
void rmsnorm_add(const float* __restrict__ x, float* __restrict__ res,
                 const float* __restrict__ w, void* __restrict__ outp,
                 int first, int bf16out) {
  const int row = blockIdx.x;
  const int tid = threadIdx.x;
  const size_t base = (size_t)row * D_;
  float4v v0 = ((const float4v*)(x + base))[tid * 2];
  float4v v1 = ((const float4v*)(x + base))[tid * 2 + 1];
  if (!first) {
    v0 += ((const float4v*)(res + base))[tid * 2];
    v1 += ((const float4v*)(res + base))[tid * 2 + 1];
  }
  ((float4v*)(res + base))[tid * 2]     = v0;
  ((float4v*)(res + base))[tid * 2 + 1] = v1;
  float ss = v0[0]*v0[0] + v0[1]*v0[1] + v0[2]*v0[2] + v0[3]*v0[3]
           + v1[0]*v1[0] + v1[1]*v1[1] + v1[2]*v1[2] + v1[3]*v1[3];
  #pragma unroll
  for (int off = 32; off > 0; off >>= 1) ss += __shfl_xor(ss, off, 64);
  __shared__ float red[4];
  if ((tid & 63) == 0) red[tid >> 6] = ss;
  __syncthreads();
  float tot = red[0] + red[1] + red[2] + red[3];
  float rs = rsqrtf(tot * (1.0f / D_) + EPS_);
  float4v w0 = ((const float4v*)w)[tid * 2];
  float4v w1 = ((const float4v*)w)[tid * 2 + 1];
  float4v o0 = v0 * rs * w0;
  float4v o1 = v1 * rs * w1;
  if (bf16out) {
    short8v y;
    #pragma unroll
    for (int k = 0; k < 4; k++) { y[k] = f2bf(o0[k]); y[k + 4] = f2bf(o1[k]); }
    ((short8v*)((char*)outp + base * 2))[tid] = y;
  } else {
    float* op = (float*)outp + base;
    ((float4v*)op)[tid * 2]     = o0;
    ((float4v*)op)[tid * 2 + 1] = o1;
  }
}

// ------- generic GEMM (m97 structure): C[M][N] f32 = A bf16 x Bt bf16 -------
#define BM 128
#define BN 128
#define BKS 32

__global__ __launch_bounds__(256)
void gemm_bf16(const short* __restrict__ A, const short* __restrict__ Bt,
               float* __restrict__ C, int M, int N, int K) {
  __shared__ short sA[BM * BKS];
  __shared__ short sB[BN * BKS];
  int bx = blockIdx.x, by = blockIdx.y;
  xcd_swizzle(gridDim.x, gridDim.y, bx, by);
  const int tid  = threadIdx.x;
  const int lane = tid & 63;
  const int wave = tid >> 6;
  const int wm = (wave >> 1) << 6;
  const int wn = (wave & 1) << 6;
  const int row0 = by * BM;
  const int col0 = bx * BN;
  const int fr = lane & 15;
  const int fk = (lane >> 4) << 3;
  float4v acc[4][4] = {};

  const int r_st  = tid >> 2;
  const int kc_st = (tid & 3) << 3;
  const short* pA = A  + (size_t)(row0 + r_st) * K + kc_st;
  const short* pB = Bt + (size_t)(col0 + r_st) * K + kc_st;
  const size_t stride64 = (size_t)64 * K;
  short* lA0 = &sA[tid * 8];
  short* lA1 = &sA[(256 + tid) * 8];
  short* lB0 = &sB[tid * 8];
  short* lB1 = &sB[(256 + tid) * 8];

  for (int k0 = 0; k0 < K; k0 += BKS) {
    GLOAD16(pA, lA0);
    GLOAD16(pA + stride64, lA1);
    GLOAD16(pB, lB0);
    GLOAD16(pB + stride64, lB1);
    pA += BKS; pB += BKS;
    __syncthreads();
    short8v af[4], bfr[4];
    #pragma unroll
    for (int f = 0; f < 4; f++) {
      af[f]  = *(const short8v*)(&sA[(wm + f * 16 + fr) * BKS + fk]);
      bfr[f] = *(const short8v*)(&sB[(wn + f * 16 + fr) * BKS + fk]);
    }
    #pragma unroll
    for (int i = 0; i < 4; i++)
      #pragma unroll
      for (int j = 0; j < 4; j++)
        acc[i][j] = __builtin_amdgcn_mfma_f32_16x16x32_bf16(af[i], bfr[j], acc[i][j], 0, 0, 0);
    __syncthreads();
  }
  const int cr = (lane >> 4) << 2;
  const int cc = lane & 15;
  #pragma unroll
  for (int i = 0; i < 4; i++)
    #pragma unroll
    for (int j = 0; j < 4; j++) {
      size_t base = (size_t)(row0 + wm + i * 16 + cr) * N + col0 + wn + j * 16 + cc;
      #pragma unroll
      for (int r = 0; r < 4; r++)
        C[base + (size_t)r * N] = acc[i][j][r];
    }
}

// ------- QKV GEMM with fused RoPE epilogue -> qbf/kbf/vbf (bf16) -------
// N = 3072 = q(2048) | k(512) | v(512); each wave's 64-col span = one head.
__global__ __launch_bounds__(256)
void gemm_qkv_rope(const short* __restrict__ A, const short* __restrict__ Bt,
                   const float* __restrict__ tab, short* __restrict__ qbf,
                   short* __restrict__ kbf, short* __restrict__ vbf, int K) {
  __shared__ short sA[BM * BKS];
  __shared__ short sB[BN * BKS];
  int bx = blockIdx.x, by = blockIdx.y;
  xcd_swizzle(gridDim.x, gridDim.y, bx, by);
  const int tid  = threadIdx.x;
  const int lane = tid & 63;
  const int wave = tid >> 6;
  const int wm = (wave >> 1) << 6;
  const int wn = (wave & 1) << 6;
  const int row0 = by * BM;
  const int col0 = bx * BN;
  const int fr = lane & 15;
  const int fk = (lane >> 4) << 3;
  float4v acc[4][4] = {};

  const int r_st  = tid >> 2;
  const int kc_st = (tid & 3) << 3;
  const short* pA = A  + (size_t)(row0 + r_st) * K + kc_st;
  const short* pB = Bt + (size_t)(col0 + r_st) * K + kc_st;
  const size_t stride64 = (size_t)64 * K;
  short* lA0 = &sA[tid * 8];
  short* lA1 = &sA[(256 + tid) * 8];
  short* lB0 = &sB[tid * 8];
  short* lB1 = &sB[(256 + tid) * 8];

  for (int k0 = 0; k0 < K; k0 += BKS) {
    GLOAD16(pA, lA0);
    GLOAD16(pA + stride64, lA1);
    GLOAD16(pB, lB0);
    GLOAD16(pB + stride64, lB1);
    pA += BKS; pB += BKS;
    __syncthreads();
    short8v af[4], bfr[4];
    #pragma unroll
    for (int f = 0; f < 4; f++) {
      af[f]  = *(const short8v*)(&sA[(wm + f * 16 + fr) * BKS + fk]);
      bfr[f] = *(const short8v*)(&sB[(wn + f * 16 + fr) * BKS + fk]);
    }
    #pragma unroll
    for (int i = 0; i < 4; i++)
      #pragma unroll
      for (int j = 0; j < 4; j++)
        acc[i][j] = __builtin_amdgcn_mfma_f32_16x16x32_bf16(af[i], bfr[j], acc[i][j], 0, 0, 0);
    __syncthreads();
  }
  const int cr = (lane >> 4) << 2;
  const int cc = lane & 15;
  const int head = (col0 + wn) >> 6;

  if (head < HQ_ + HKV_) {
    // q or k head: rope pairs are tiles (j, j+2)
    const float sc = (head < HQ_) ? SCALE_ : 1.0f;
    #pragma unroll
    for (int i = 0; i < 4; i++)
      #pragma unroll
      for (int jj = 0; jj < 2; jj++)
        #pragma unroll
        for (int r = 0; r < 4; r++) {
          int m = row0 + wm + i * 16 + cr + r;
          int b = m >> 10, s = m & (S_ - 1);
          int d1 = jj * 16 + cc;
          float x1 = acc[i][jj][r], x2 = acc[i][jj + 2][r];
          const float* tb = tab + (size_t)m * 64 + d1 * 2;
          float c = tb[0], sn = tb[1];
          short y1 = f2bf((x1 * c - x2 * sn) * sc);
          short y2 = f2bf((x2 * c + x1 * sn) * sc);
          size_t base;
          if (head < HQ_)
            base = ((size_t)((b * HQ_ + head) * S_ + s)) * HD_;
          else
            base = ((size_t)((b * HKV_ + head - HQ_) * S_ + s)) * HD_;
          short* dst = (head < HQ_) ? qbf : kbf;
          dst[base + d1]      = y1;
          dst[base + d1 + 32] = y2;
        }
  } else {
    const int vh = head - HQ_ - HKV_;
    #pragma unroll
    for (int i = 0; i < 4; i++)
      #pragma unroll
      for (int j = 0; j < 4; j++)
        #pragma unroll
        for (int r = 0; r < 4; r++) {
          int m = row0 + wm + i * 16 + cr + r;
          int b = m >> 10, s = m & (S_ - 1);
          vbf[((size_t)((b * HKV_ + vh) * S_ + s)) * HD_ + j * 16 + cc] =
              f2bf(acc[i][j][r]);
        }
  }
}

// ------- gate_up GEMM with fused SwiGLU epilogue -> mlpbf (bf16) -------
// Block computes gate tile [col0,col0+128) and up tile [col0+I_, ...) off one A.
__global__ __launch_bounds__(256)
void gemm_glu(const short* __restrict__ A, const short* __restrict__ Bt,
              short* __restrict__ mlp, int K) {
  __shared__ short sA[BM * BKS];
  __shared__ short sG[BN * BKS];
  __shared__ short sU[BN * BKS];
  int bx = blockIdx.x, by = blockIdx.y;
  xcd_swizzle(gridDim.x, gridDim.y, bx, by);
  const int tid  = threadIdx.x;
  const int lane = tid & 63;
  const int wave = tid >> 6;
  const int wm = (wave >> 1) << 6;
  const int wn = (wave & 1) << 6;
  const int row0 = by * BM;
  const int col0 = bx * BN;
  const int fr = lane & 15;
  const int fk = (lane >> 4) << 3;
  float4v accg[4][4] = {};
  float4v accu[4][4] = {};

  const int r_st  = tid >> 2;
  const int kc_st = (tid & 3) << 3;
  const short* pA = A  + (size_t)(row0 + r_st) * K + kc_st;
  const short* pG = Bt + (size_t)(col0 + r_st) * K + kc_st;
  const short* pU = Bt + (size_t)(col0 + I_ + r_st) * K + kc_st;
  const size_t stride64 = (size_t)64 * K;
  short* lA0 = &sA[tid * 8];
  short* lA1 = &sA[(256 + tid) * 8];
  short* lG0 = &sG[tid * 8];
  short* lG1 = &sG[(256 + tid) * 8];
  short* lU0 = &sU[tid * 8];
  short* lU1 = &sU[(256 + tid) * 8];

  for (int k0 = 0; k0 < K; k0 += BKS) {
    GLOAD16(pA, lA0);
    GLOAD16(pA + stride64, lA1);
    GLOAD16(pG, lG0);
    GLOAD16(pG + stride64, lG1);
    GLOAD16(pU, lU0);
    GLOAD16(pU + stride64, lU1);
    pA += BKS; pG += BKS; pU += BKS;
    __syncthreads();
    short8v af[4], bg[4], bu[4];
    #pragma unroll
    for (int f = 0; f < 4; f++) {
      af[f] = *(const short8v*)(&sA[(wm + f * 16 + fr) * BKS + fk]);
      bg[f] = *(const short8v*)(&sG[(wn + f * 16 + fr) * BKS + fk]);
      bu[f] = *(const short8v*)(&sU[(wn + f * 16 + fr) * BKS + fk]);
    }
    #pragma unroll
    for (int i = 0; i < 4; i++)
      #pragma unroll
      for (int j = 0; j < 4; j++) {
        accg[i][j] = __builtin_amdgcn_mfma_f32_16x16x32_bf16(af[i], bg[j], accg[i][j], 0, 0, 0);
        accu[i][j] = __builtin_amdgcn_mfma_f32_16x16x32_bf16(af[i], bu[j], accu[i][j], 0, 0, 0);
      }
    __syncthreads();
  }
  const int cr = (lane >> 4) << 2;
  const int cc = lane & 15;
  #pragma unroll
  for (int i = 0; i < 4; i++)
    #pragma unroll
    for (int j = 0; j < 4; j++) {
      size_t base = (size_t)(row0 + wm + i * 16 + cr) * I_ + col0 + wn + j * 16 + cc;
      #pragma unroll
      for (int r = 0; r < 4; r++) {
        float g = accg[i][j][r], u = accu[i][j][r];
        mlp[base + (size_t)r * I_] = f2bf(g / (1.0f + __expf(-g)) * u);
      }
    }
}

// ---------------- RoPE cos/sin table: [T][32][2] f32 ----------------
__global__ __launch_bounds__(256)
void rope_table(const int* __restrict__ pos, float* __restrict__ tab) {
  int i = blockIdx.x * 256 + threadIdx.x;
  int t = i >> 5, ii = i & 31;
  float p = (float)pos[t];
  float freq = __expf(-(float)ii * (9.210340371976184f / 32.0f));
  float ang = p * freq;
  tab[2 * i]     = cosf(ang);
  tab[2 * i + 1] = sinf(ang);
}

// ---------------- V transpose: vbf [bkh][j][d] -> vtbf [bkh][d][j] ----------------
#define KPAD 68

__global__ __launch_bounds__(256)
void transpose_v(const short* __restrict__ vbf, short* __restrict__ vtbf) {
  __shared__ short sv[64 * KPAD];
  const int jt = blockIdx.x, kh = blockIdx.y, b = blockIdx.z;
  const int tid = threadIdx.x;
  const short* src = vbf + ((size_t)((b * HKV_ + kh) * S_ + jt * 64)) * HD_;
  #pragma unroll
  for (int it = 0; it < 2; it++) {
    int c = it * 256 + tid;
    int rr = c >> 3, ch = (c & 7) * 8;
    *(short8v*)(&sv[rr * KPAD + ch]) = *(const short8v*)(src + (size_t)rr * HD_ + ch);
  }
  __syncthreads();
  const int dc = tid >> 2;
  const int jc = (tid & 3) * 16;
  short8v o1, o2;
  #pragma unroll
  for (int k = 0; k < 8; k++) o1[k] = sv[(jc + k) * KPAD + dc];
  #pragma unroll
  for (int k = 0; k < 8; k++) o2[k] = sv[(jc + 8 + k) * KPAD + dc];
  short* od = vtbf + ((size_t)((b * HKV_ + kh) * HD_ + dc)) * S_ + jt * 64 + jc;
  *(short8v*)od       = o1;
  *(short8v*)(od + 8) = o2;
}

// ---------------- MFMA flash attention (bf16 out) ----------------
__global__ __launch_bounds__(256)
void attn_mfma(const short* __restrict__ qbf, const short* __restrict__ kbf,
               const short* __restrict__ vtbf, short* __restrict__ obf) {
  __shared__ short sK[64 * KPAD];
  __shared__ short sVt[64 * KPAD];
  __shared__ short sP[4][16 * KPAD];
  const int qb = blockIdx.x;
  const int h  = blockIdx.y;
  const int b  = blockIdx.z;
  const int kh = h >> 2;
  const int tid  = threadIdx.x;
  const int lane = tid & 63;
  const int wv   = tid >> 6;
  const int q0 = qb * 64;
  const int cc = lane & 15;
  const int g  = lane >> 4;

  short8v qf0, qf1;
  {
    const short* qrow = qbf + ((size_t)((b * HQ_ + h) * S_ + q0 + wv * 16 + cc)) * HD_;
    qf0 = *(const short8v*)(qrow + g * 8);
    qf1 = *(const short8v*)(qrow + g * 8 + 32);
  }
  float4v accO[4] = {};
  float m_r[4], l_r[4];
  #pragma unroll
  for (int r = 0; r < 4; r++) { m_r[r] = -1e30f; l_r[r] = 0.f; }

  const short* kb = kbf  + ((size_t)(b * HKV_ + kh)) * S_ * HD_;
  const short* vb = vtbf + ((size_t)(b * HKV_ + kh)) * HD_ * S_;

  for (int jt = 0; jt <= qb; jt++) {
    const int j0 = jt * 64;
    #pragma unroll
    for (int it = 0; it < 2; it++) {
      int idx = it * 256 + tid;
      int rr = idx >> 3, ch = (idx & 7) * 8;
      *(short8v*)(&sK[rr * KPAD + ch])  = *(const short8v*)(kb + (size_t)(j0 + rr) * HD_ + ch);
      *(short8v*)(&sVt[rr * KPAD + ch]) = *(const short8v*)(vb + (size_t)rr * S_ + j0 + ch);
    }
    __syncthreads();

    float4v sc[4] = {};
    #pragma unroll
    for (int ct = 0; ct < 4; ct++) {
      short8v k0 = *(const short8v*)(&sK[(ct * 16 + cc) * KPAD + g * 8]);
      short8v k1 = *(const short8v*)(&sK[(ct * 16 + cc) * KPAD + g * 8 + 32]);
      sc[ct] = __builtin_amdgcn_mfma_f32_16x16x32_bf16(qf0, k0, sc[ct], 0, 0, 0);
      sc[ct] = __builtin_amdgcn_mfma_f32_16x16x32_bf16(qf1, k1, sc[ct], 0, 0, 0);
    }
    if (jt == qb) {
      #pragma unroll
      for (int ct = 0; ct < 4; ct++)
        #pragma unroll
        for (int r = 0; r < 4; r++)
          if (j0 + ct * 16 + cc > q0 + wv * 16 + g * 4 + r) sc[ct][r] = -1e30f;
    }
    float corr[4];
    #pragma unroll
    for (int r = 0; r < 4; r++) {
      float pm = fmaxf(fmaxf(sc[0][r], sc[1][r]), fmaxf(sc[2][r], sc[3][r]));
      pm = fmaxf(pm, __shfl_xor(pm, 1, 64));
      pm = fmaxf(pm, __shfl_xor(pm, 2, 64));
      pm = fmaxf(pm, __shfl_xor(pm, 4, 64));
      pm = fmaxf(pm, __shfl_xor(pm, 8, 64));
      float mn = fmaxf(m_r[r], pm);
      corr[r] = __expf(m_r[r] - mn);
      m_r[r] = mn;
      float rs = 0.f;
      #pragma unroll
      for (int ct = 0; ct < 4; ct++) {
        float p = __expf(sc[ct][r] - mn);
        sc[ct][r] = p;
        rs += p;
      }
      rs += __shfl_xor(rs, 1, 64);
      rs += __shfl_xor(rs, 2, 64);
      rs += __shfl_xor(rs, 4, 64);
      rs += __shfl_xor(rs, 8, 64);
      l_r[r] = l_r[r] * corr[r] + rs;
    }
    #pragma unroll
    for (int ct = 0; ct < 4; ct++)
      #pragma unroll
      for (int r = 0; r < 4; r++)
        sP[wv][(g * 4 + r) * KPAD + ct * 16 + cc] = f2bf(sc[ct][r]);
    #pragma unroll
    for (int dt = 0; dt < 4; dt++)
      #pragma unroll
      for (int r = 0; r < 4; r++)
        accO[dt][r] *= corr[r];
    short8v pf0 = *(const short8v*)(&sP[wv][cc * KPAD + g * 8]);
    short8v pf1 = *(const short8v*)(&sP[wv][cc * KPAD + g * 8 + 32]);
    #pragma unroll
    for (int dt = 0; dt < 4; dt++) {
      short8v v0 = *(const short8v*)(&sVt[(dt * 16 + cc) * KPAD + g * 8]);
      short8v v1 = *(const short8v*)(&sVt[(dt * 16 + cc) * KPAD + g * 8 + 32]);
      accO[dt] = __builtin_amdgcn_mfma_f32_16x16x32_bf16(pf0, v0, accO[dt], 0, 0, 0);
      accO[dt] = __builtin_amdgcn_mfma_f32_16x16x32_bf16(pf1, v1, accO[dt], 0, 0, 0);
    }
    __syncthreads();
  }
  #pragma unroll
  for (int dt = 0; dt < 4; dt++)
    #pragma unroll
    for (int r = 0; r < 4; r++) {
      int q = q0 + wv * 16 + g * 4 + r;
      obf[((size_t)(b * S_ + q)) * 2048 + h * 64 + dt * 16 + cc] = f2bf(accO[dt][r] / l_r[r]);
    }
}

// ---------------- launch ----------------
extern "C" void kernel_launch(void* const* d_in, const int* in_sizes, int n_in,
                              void* d_out, int out_size, void* d_ws, size_t ws_size,
                              hipStream_t stream) {
  const int*   ids   = (const int*)d_in[0];
  const int*   pos   = (const int*)d_in[1];
  const float* embed = (const float*)d_in[2];
  const float* w_qkv = (const float*)d_in[3];
  const float* w_o   = (const float*)d_in[4];
  const float* w_gu  = (const float*)d_in[5];
  const float* w_dn  = (const float*)d_in[6];
  const float* ln1   = (const float*)d_in[7];
  const float* ln2   = (const float*)d_in[8];
  const float* normw = (const float*)d_in[9];
  float* out = (float*)d_out;

  char* p = (char*)d_ws;
  short* wT    = (short*)p; p += (size_t)11264 * 2048 * 2;
  float* h     = (float*)p; p += (size_t)T_ * D_ * 4;
  float* res   = (float*)p; p += (size_t)T_ * D_ * 4;
  short* hnbf  = (short*)p; p += (size_t)T_ * D_ * 2;
  short* obf   = (short*)p; p += (size_t)T_ * D_ * 2;
  short* mlpbf = (short*)p; p += (size_t)T_ * I_ * 2;
  float* tab   = (float*)p; p += (size_t)T_ * 64 * 4;
  short* qbf   = (short*)p; p += (size_t)B_ * HQ_ * S_ * HD_ * 2;
  short* kbf   = (short*)p; p += (size_t)B_ * HKV_ * S_ * HD_ * 2;
  short* vbf   = (short*)p; p += (size_t)B_ * HKV_ * S_ * HD_ * 2;
  short* vtbf  = (short*)p; p += (size_t)B_ * HKV_ * HD_ * S_ * 2;

  dim3 tb(32, 8);
  embed_gather<<<T_ * D_ / 4 / 256, 256, 0, stream>>>(ids, embed, h);
  rope_table<<<T_ * 32 / 256, 256, 0, stream>>>(pos, tab);

  for (int l = 0; l < L_; l++) {
    rmsnorm_add<<<T_, 256, 0, stream>>>(h, res, ln1 + l * D_, hnbf, l == 0 ? 1 : 0, 1);

    transpose_bf16<<<dim3(3072 / 32, 2048 / 32), tb, 0, stream>>>(
        w_qkv + (size_t)l * 2048 * 3072, wT, 2048, 3072);
    gemm_qkv_rope<<<dim3(3072 / BN, T_ / BM), 256, 0, stream>>>(
        hnbf, wT, tab, qbf, kbf, vbf, 2048);

    transpose_v<<<dim3(16, 8, 2), 256, 0, stream>>>(vbf, vtbf);
    attn_mfma<<<dim3(16, 32, 2), 256, 0, stream>>>(qbf, kbf, vtbf, obf);

    transpose_bf16<<<dim3(2048 / 32, 2048 / 32), tb, 0, stream>>>(
        w_o + (size_t)l * 2048 * 2048, wT, 2048, 2048);
    gemm_bf16<<<dim3(2048 / BN, T_ / BM), 256, 0, stream>>>(
        obf, wT, h, T_, 2048, 2048);

    rmsnorm_add<<<T_, 256, 0, stream>>>(h, res, ln2 + l * D_, hnbf, 0, 1);

    transpose_bf16<<<dim3(11264 / 32, 2048 / 32), tb, 0, stream>>>(
        w_gu + (size_t)l * 2048 * 11264, wT, 2048, 11264);
    gemm_glu<<<dim3(I_ / BN, T_ / BM), 256, 0, stream>>>(
        hnbf, wT, mlpbf, 2048);

    transpose_bf16<<<dim3(2048 / 32, 5632 / 32), tb, 0, stream>>>(
        w_dn + (size_t)l * 5632 * 2048, wT, 5632, 2048);
    gemm_bf16<<<dim3(2048 / BN, T_ / BM), 256, 0, stream>>>(
        mlpbf, wT, h, T_, 2048, 5632);
  }
  rmsnorm_add<<<T_, 256, 0, stream>>>(h, res, normw, out, 0, 0);
}

// Round 5
// 1938.959 us; speedup vs baseline: 1.2704x; 1.2704x over previous
//
#include <hip/hip_runtime.h>
#include <hip/hip_bf16.h>

#define B_ 2
#define S_ 1024
#define T_ (B_*S_)
#define D_ 2048
#define L_ 4
#define HQ_ 32
#define HKV_ 8
#define HD_ 64
#define I_ 5632
#define EPS_ 1e-5f
#define SCALE_ 0.125f

typedef __attribute__((ext_vector_type(4))) float  float4v;
typedef __attribute__((ext_vector_type(8))) short  short8v;

#define GLOAD16(g, l) \
  __builtin_amdgcn_global_load_lds((const __attribute__((address_space(1))) void*)(g), \
                                   (__attribute__((address_space(3))) void*)(l), 16, 0, 0)

__device__ __forceinline__ short f2bf(float f) {
  union { float f; unsigned u; } c; c.f = f;
  unsigned u = c.u + 0x7fffu + ((c.u >> 16) & 1u);
  return (short)(u >> 16);
}

// bijective XCD-aware block swizzle (m204), column-major decode
__device__ __forceinline__ void xcd_swizzle(int gx, int gy, int& bx, int& by) {
  int nwg = gx * gy;
  int orig = by * gx + bx;
  int q = nwg >> 3, r = nwg & 7;
  int xcd = orig & 7, loc = orig >> 3;
  int swz = (xcd < r ? xcd * (q + 1) : r * (q + 1) + (xcd - r) * q) + loc;
  bx = swz / gy;
  by = swz - bx * gy;
}

// ---------------- transpose f32 [K][N] -> bf16 [N][K] ----------------
__global__ __launch_bounds__(256)
void transpose_bf16(const float* __restrict__ in, short* __restrict__ out,
                    int K, int N) {
  __shared__ float t[32][33];
  const int bx = blockIdx.x * 32;
  const int by = blockIdx.y * 32;
  const int tx = threadIdx.x, ty = threadIdx.y;
  #pragma unroll
  for (int j = 0; j < 32; j += 8)
    t[ty + j][tx] = in[(size_t)(by + ty + j) * N + bx + tx];
  __syncthreads();
  #pragma unroll
  for (int j = 0; j < 32; j += 8)
    out[(size_t)(bx + ty + j) * K + by + tx] = f2bf(t[tx][ty + j]);
}

// ---------------- embedding gather ----------------
__global__ __launch_bounds__(256)
void embed_gather(const int* __restrict__ ids, const float* __restrict__ embed,
                  float* __restrict__ h) {
  size_t i = (size_t)blockIdx.x * 256 + threadIdx.x;
  int t  = (int)(i >> 9);
  int d4 = (int)(i & 511);
  ((float4v*)h)[i] = ((const float4v*)(embed + (size_t)ids[t] * D_))[d4];
}

// ---------------- fused residual-add + RMSNorm (bf16 or f32 out) ----------------
__global__ __launch_bounds__(256)
void rmsnorm_add(const float* __restrict__ x, float* __restrict__ res,
                 const float* __restrict__ w, void* __restrict__ outp,
                 int first, int bf16out) {
  const int row = blockIdx.x;
  const int tid = threadIdx.x;
  const size_t base = (size_t)row * D_;
  float4v v0 = ((const float4v*)(x + base))[tid * 2];
  float4v v1 = ((const float4v*)(x + base))[tid * 2 + 1];
  if (!first) {
    v0 += ((const float4v*)(res + base))[tid * 2];
    v1 += ((const float4v*)(res + base))[tid * 2 + 1];
  }
  ((float4v*)(res + base))[tid * 2]     = v0;
  ((float4v*)(res + base))[tid * 2 + 1] = v1;
  float ss = v0[0]*v0[0] + v0[1]*v0[1] + v0[2]*v0[2] + v0[3]*v0[3]
           + v1[0]*v1[0] + v1[1]*v1[1] + v1[2]*v1[2] + v1[3]*v1[3];
  #pragma unroll
  for (int off = 32; off > 0; off >>= 1) ss += __shfl_xor(ss, off, 64);
  __shared__ float red[4];
  if ((tid & 63) == 0) red[tid >> 6] = ss;
  __syncthreads();
  float tot = red[0] + red[1] + red[2] + red[3];
  float rs = rsqrtf(tot * (1.0f / D_) + EPS_);
  float4v w0 = ((const float4v*)w)[tid * 2];
  float4v w1 = ((const float4v*)w)[tid * 2 + 1];
  float4v o0 = v0 * rs * w0;
  float4v o1 = v1 * rs * w1;
  if (bf16out) {
    short8v y;
    #pragma unroll
    for (int k = 0; k < 4; k++) { y[k] = f2bf(o0[k]); y[k + 4] = f2bf(o1[k]); }
    ((short8v*)((char*)outp + base * 2))[tid] = y;
  } else {
    float* op = (float*)outp + base;
    ((float4v*)op)[tid * 2]     = o0;
    ((float4v*)op)[tid * 2 + 1] = o1;
  }
}

#define BM 128
#define BN 128
#define BKS 32

// ------- plain GEMM, BN=64 (2 blocks/CU for N=2048 shapes) -------
// C[M][N] f32 = A[M][K] bf16 x Bt[N][K] bf16; wave tile 64x32
__global__ __launch_bounds__(256)
void gemm_n64(const short* __restrict__ A, const short* __restrict__ Bt,
              float* __restrict__ C, int M, int N, int K) {
  __shared__ short sA[BM * BKS];     // 8 KB
  __shared__ short sB[64 * BKS];     // 4 KB
  int bx = blockIdx.x, by = blockIdx.y;
  xcd_swizzle(gridDim.x, gridDim.y, bx, by);
  const int tid  = threadIdx.x;
  const int lane = tid & 63;
  const int wave = tid >> 6;
  const int wm = (wave >> 1) << 6;   // 2x2 waves, wave tile 64x32
  const int wn = (wave & 1) << 5;
  const int row0 = by * BM;
  const int col0 = bx * 64;
  const int fr = lane & 15;
  const int fk = (lane >> 4) << 3;
  float4v acc[4][2] = {};

  const int r_st  = tid >> 2;
  const int kc_st = (tid & 3) << 3;
  const short* pA = A  + (size_t)(row0 + r_st) * K + kc_st;
  const short* pB = Bt + (size_t)(col0 + r_st) * K + kc_st;
  const size_t stride64 = (size_t)64 * K;
  short* lA0 = &sA[tid * 8];
  short* lA1 = &sA[(256 + tid) * 8];
  short* lB0 = &sB[tid * 8];

  for (int k0 = 0; k0 < K; k0 += BKS) {
    GLOAD16(pA, lA0);
    GLOAD16(pA + stride64, lA1);
    GLOAD16(pB, lB0);
    pA += BKS; pB += BKS;
    __syncthreads();
    short8v af[4], bfr[2];
    #pragma unroll
    for (int f = 0; f < 4; f++)
      af[f] = *(const short8v*)(&sA[(wm + f * 16 + fr) * BKS + fk]);
    #pragma unroll
    for (int f = 0; f < 2; f++)
      bfr[f] = *(const short8v*)(&sB[(wn + f * 16 + fr) * BKS + fk]);
    #pragma unroll
    for (int i = 0; i < 4; i++)
      #pragma unroll
      for (int j = 0; j < 2; j++)
        acc[i][j] = __builtin_amdgcn_mfma_f32_16x16x32_bf16(af[i], bfr[j], acc[i][j], 0, 0, 0);
    __syncthreads();
  }
  const int cr = (lane >> 4) << 2;
  const int cc = lane & 15;
  #pragma unroll
  for (int i = 0; i < 4; i++)
    #pragma unroll
    for (int j = 0; j < 2; j++) {
      size_t base = (size_t)(row0 + wm + i * 16 + cr) * N + col0 + wn + j * 16 + cc;
      #pragma unroll
      for (int r = 0; r < 4; r++)
        C[base + (size_t)r * N] = acc[i][j][r];
    }
}

// ------- gate_up GEMM + fused SwiGLU, BN=64 -------
// gate rows [col0,col0+64), up rows [col0+I_, ...); out bf16 [M][I_]
__global__ __launch_bounds__(256)
void gemm_glu(const short* __restrict__ A, const short* __restrict__ Bt,
              short* __restrict__ mlp, int K) {
  __shared__ short sA[BM * BKS];     // 8 KB
  __shared__ short sG[64 * BKS];     // 4 KB
  __shared__ short sU[64 * BKS];     // 4 KB
  int bx = blockIdx.x, by = blockIdx.y;
  xcd_swizzle(gridDim.x, gridDim.y, bx, by);
  const int tid  = threadIdx.x;
  const int lane = tid & 63;
  const int wave = tid >> 6;
  const int wm = (wave >> 1) << 6;
  const int wn = (wave & 1) << 5;
  const int row0 = by * BM;
  const int col0 = bx * 64;
  const int fr = lane & 15;
  const int fk = (lane >> 4) << 3;
  float4v accg[4][2] = {};
  float4v accu[4][2] = {};

  const int r_st  = tid >> 2;
  const int kc_st = (tid & 3) << 3;
  const short* pA = A  + (size_t)(row0 + r_st) * K + kc_st;
  const short* pG = Bt + (size_t)(col0 + r_st) * K + kc_st;
  const short* pU = Bt + (size_t)(col0 + I_ + r_st) * K + kc_st;
  const size_t stride64 = (size_t)64 * K;
  short* lA0 = &sA[tid * 8];
  short* lA1 = &sA[(256 + tid) * 8];
  short* lG0 = &sG[tid * 8];
  short* lU0 = &sU[tid * 8];

  for (int k0 = 0; k0 < K; k0 += BKS) {
    GLOAD16(pA, lA0);
    GLOAD16(pA + stride64, lA1);
    GLOAD16(pG, lG0);
    GLOAD16(pU, lU0);
    pA += BKS; pG += BKS; pU += BKS;
    __syncthreads();
    short8v af[4], bg[2], bu[2];
    #pragma unroll
    for (int f = 0; f < 4; f++)
      af[f] = *(const short8v*)(&sA[(wm + f * 16 + fr) * BKS + fk]);
    #pragma unroll
    for (int f = 0; f < 2; f++) {
      bg[f] = *(const short8v*)(&sG[(wn + f * 16 + fr) * BKS + fk]);
      bu[f] = *(const short8v*)(&sU[(wn + f * 16 + fr) * BKS + fk]);
    }
    #pragma unroll
    for (int i = 0; i < 4; i++)
      #pragma unroll
      for (int j = 0; j < 2; j++) {
        accg[i][j] = __builtin_amdgcn_mfma_f32_16x16x32_bf16(af[i], bg[j], accg[i][j], 0, 0, 0);
        accu[i][j] = __builtin_amdgcn_mfma_f32_16x16x32_bf16(af[i], bu[j], accu[i][j], 0, 0, 0);
      }
    __syncthreads();
  }
  const int cr = (lane >> 4) << 2;
  const int cc = lane & 15;
  #pragma unroll
  for (int i = 0; i < 4; i++)
    #pragma unroll
    for (int j = 0; j < 2; j++) {
      size_t base = (size_t)(row0 + wm + i * 16 + cr) * I_ + col0 + wn + j * 16 + cc;
      #pragma unroll
      for (int r = 0; r < 4; r++) {
        float g = accg[i][j][r], u = accu[i][j][r];
        mlp[base + (size_t)r * I_] = f2bf(g / (1.0f + __expf(-g)) * u);
      }
    }
}

// ------- QKV GEMM with fused RoPE epilogue (128x128, proven) -------
__global__ __launch_bounds__(256)
void gemm_qkv_rope(const short* __restrict__ A, const short* __restrict__ Bt,
                   const float* __restrict__ tab, short* __restrict__ qbf,
                   short* __restrict__ kbf, short* __restrict__ vbf, int K) {
  __shared__ short sA[BM * BKS];
  __shared__ short sB[BN * BKS];
  int bx = blockIdx.x, by = blockIdx.y;
  xcd_swizzle(gridDim.x, gridDim.y, bx, by);
  const int tid  = threadIdx.x;
  const int lane = tid & 63;
  const int wave = tid >> 6;
  const int wm = (wave >> 1) << 6;
  const int wn = (wave & 1) << 6;
  const int row0 = by * BM;
  const int col0 = bx * BN;
  const int fr = lane & 15;
  const int fk = (lane >> 4) << 3;
  float4v acc[4][4] = {};

  const int r_st  = tid >> 2;
  const int kc_st = (tid & 3) << 3;
  const short* pA = A  + (size_t)(row0 + r_st) * K + kc_st;
  const short* pB = Bt + (size_t)(col0 + r_st) * K + kc_st;
  const size_t stride64 = (size_t)64 * K;
  short* lA0 = &sA[tid * 8];
  short* lA1 = &sA[(256 + tid) * 8];
  short* lB0 = &sB[tid * 8];
  short* lB1 = &sB[(256 + tid) * 8];

  for (int k0 = 0; k0 < K; k0 += BKS) {
    GLOAD16(pA, lA0);
    GLOAD16(pA + stride64, lA1);
    GLOAD16(pB, lB0);
    GLOAD16(pB + stride64, lB1);
    pA += BKS; pB += BKS;
    __syncthreads();
    short8v af[4], bfr[4];
    #pragma unroll
    for (int f = 0; f < 4; f++) {
      af[f]  = *(const short8v*)(&sA[(wm + f * 16 + fr) * BKS + fk]);
      bfr[f] = *(const short8v*)(&sB[(wn + f * 16 + fr) * BKS + fk]);
    }
    #pragma unroll
    for (int i = 0; i < 4; i++)
      #pragma unroll
      for (int j = 0; j < 4; j++)
        acc[i][j] = __builtin_amdgcn_mfma_f32_16x16x32_bf16(af[i], bfr[j], acc[i][j], 0, 0, 0);
    __syncthreads();
  }
  const int cr = (lane >> 4) << 2;
  const int cc = lane & 15;
  const int head = (col0 + wn) >> 6;

  if (head < HQ_ + HKV_) {
    const float sc = (head < HQ_) ? SCALE_ : 1.0f;
    #pragma unroll
    for (int i = 0; i < 4; i++)
      #pragma unroll
      for (int jj = 0; jj < 2; jj++)
        #pragma unroll
        for (int r = 0; r < 4; r++) {
          int m = row0 + wm + i * 16 + cr + r;
          int b = m >> 10, s = m & (S_ - 1);
          int d1 = jj * 16 + cc;
          float x1 = acc[i][jj][r], x2 = acc[i][jj + 2][r];
          const float* tb = tab + (size_t)m * 64 + d1 * 2;
          float c = tb[0], sn = tb[1];
          short y1 = f2bf((x1 * c - x2 * sn) * sc);
          short y2 = f2bf((x2 * c + x1 * sn) * sc);
          size_t base;
          if (head < HQ_)
            base = ((size_t)((b * HQ_ + head) * S_ + s)) * HD_;
          else
            base = ((size_t)((b * HKV_ + head - HQ_) * S_ + s)) * HD_;
          short* dst = (head < HQ_) ? qbf : kbf;
          dst[base + d1]      = y1;
          dst[base + d1 + 32] = y2;
        }
  } else {
    const int vh = head - HQ_ - HKV_;
    #pragma unroll
    for (int i = 0; i < 4; i++)
      #pragma unroll
      for (int j = 0; j < 4; j++)
        #pragma unroll
        for (int r = 0; r < 4; r++) {
          int m = row0 + wm + i * 16 + cr + r;
          int b = m >> 10, s = m & (S_ - 1);
          vbf[((size_t)((b * HKV_ + vh) * S_ + s)) * HD_ + j * 16 + cc] =
              f2bf(acc[i][j][r]);
        }
  }
}

// ---------------- RoPE cos/sin table: [T][32][2] f32 ----------------
__global__ __launch_bounds__(256)
void rope_table(const int* __restrict__ pos, float* __restrict__ tab) {
  int i = blockIdx.x * 256 + threadIdx.x;
  int t = i >> 5, ii = i & 31;
  float p = (float)pos[t];
  float freq = __expf(-(float)ii * (9.210340371976184f / 32.0f));
  float ang = p * freq;
  tab[2 * i]     = cosf(ang);
  tab[2 * i + 1] = sinf(ang);
}

// ---------------- V transpose: vbf [bkh][j][d] -> vtbf [bkh][d][j] ----------------
#define KPAD 68

__global__ __launch_bounds__(256)
void transpose_v(const short* __restrict__ vbf, short* __restrict__ vtbf) {
  __shared__ short sv[64 * KPAD];
  const int jt = blockIdx.x, kh = blockIdx.y, b = blockIdx.z;
  const int tid = threadIdx.x;
  const short* src = vbf + ((size_t)((b * HKV_ + kh) * S_ + jt * 64)) * HD_;
  #pragma unroll
  for (int it = 0; it < 2; it++) {
    int c = it * 256 + tid;
    int rr = c >> 3, ch = (c & 7) * 8;
    *(short8v*)(&sv[rr * KPAD + ch]) = *(const short8v*)(src + (size_t)rr * HD_ + ch);
  }
  __syncthreads();
  const int dc = tid >> 2;
  const int jc = (tid & 3) * 16;
  short8v o1, o2;
  #pragma unroll
  for (int k = 0; k < 8; k++) o1[k] = sv[(jc + k) * KPAD + dc];
  #pragma unroll
  for (int k = 0; k < 8; k++) o2[k] = sv[(jc + 8 + k) * KPAD + dc];
  short* od = vtbf + ((size_t)((b * HKV_ + kh) * HD_ + dc)) * S_ + jt * 64 + jc;
  *(short8v*)od       = o1;
  *(short8v*)(od + 8) = o2;
}

// ---------------- MFMA flash attention (bf16 out) ----------------
__global__ __launch_bounds__(256)
void attn_mfma(const short* __restrict__ qbf, const short* __restrict__ kbf,
               const short* __restrict__ vtbf, short* __restrict__ obf) {
  __shared__ short sK[64 * KPAD];
  __shared__ short sVt[64 * KPAD];
  __shared__ short sP[4][16 * KPAD];
  const int qb = blockIdx.x;
  const int h  = blockIdx.y;
  const int b  = blockIdx.z;
  const int kh = h >> 2;
  const int tid  = threadIdx.x;
  const int lane = tid & 63;
  const int wv   = tid >> 6;
  const int q0 = qb * 64;
  const int cc = lane & 15;
  const int g  = lane >> 4;

  short8v qf0, qf1;
  {
    const short* qrow = qbf + ((size_t)((b * HQ_ + h) * S_ + q0 + wv * 16 + cc)) * HD_;
    qf0 = *(const short8v*)(qrow + g * 8);
    qf1 = *(const short8v*)(qrow + g * 8 + 32);
  }
  float4v accO[4] = {};
  float m_r[4], l_r[4];
  #pragma unroll
  for (int r = 0; r < 4; r++) { m_r[r] = -1e30f; l_r[r] = 0.f; }

  const short* kb = kbf  + ((size_t)(b * HKV_ + kh)) * S_ * HD_;
  const short* vb = vtbf + ((size_t)(b * HKV_ + kh)) * HD_ * S_;

  for (int jt = 0; jt <= qb; jt++) {
    const int j0 = jt * 64;
    #pragma unroll
    for (int it = 0; it < 2; it++) {
      int idx = it * 256 + tid;
      int rr = idx >> 3, ch = (idx & 7) * 8;
      *(short8v*)(&sK[rr * KPAD + ch])  = *(const short8v*)(kb + (size_t)(j0 + rr) * HD_ + ch);
      *(short8v*)(&sVt[rr * KPAD + ch]) = *(const short8v*)(vb + (size_t)rr * S_ + j0 + ch);
    }
    __syncthreads();

    float4v sc[4] = {};
    #pragma unroll
    for (int ct = 0; ct < 4; ct++) {
      short8v k0 = *(const short8v*)(&sK[(ct * 16 + cc) * KPAD + g * 8]);
      short8v k1 = *(const short8v*)(&sK[(ct * 16 + cc) * KPAD + g * 8 + 32]);
      sc[ct] = __builtin_amdgcn_mfma_f32_16x16x32_bf16(qf0, k0, sc[ct], 0, 0, 0);
      sc[ct] = __builtin_amdgcn_mfma_f32_16x16x32_bf16(qf1, k1, sc[ct], 0, 0, 0);
    }
    if (jt == qb) {
      #pragma unroll
      for (int ct = 0; ct < 4; ct++)
        #pragma unroll
        for (int r = 0; r < 4; r++)
          if (j0 + ct * 16 + cc > q0 + wv * 16 + g * 4 + r) sc[ct][r] = -1e30f;
    }
    float corr[4];
    #pragma unroll
    for (int r = 0; r < 4; r++) {
      float pm = fmaxf(fmaxf(sc[0][r], sc[1][r]), fmaxf(sc[2][r], sc[3][r]));
      pm = fmaxf(pm, __shfl_xor(pm, 1, 64));
      pm = fmaxf(pm, __shfl_xor(pm, 2, 64));
      pm = fmaxf(pm, __shfl_xor(pm, 4, 64));
      pm = fmaxf(pm, __shfl_xor(pm, 8, 64));
      float mn = fmaxf(m_r[r], pm);
      corr[r] = __expf(m_r[r] - mn);
      m_r[r] = mn;
      float rs = 0.f;
      #pragma unroll
      for (int ct = 0; ct < 4; ct++) {
        float p = __expf(sc[ct][r] - mn);
        sc[ct][r] = p;
        rs += p;
      }
      rs += __shfl_xor(rs, 1, 64);
      rs += __shfl_xor(rs, 2, 64);
      rs += __shfl_xor(rs, 4, 64);
      rs += __shfl_xor(rs, 8, 64);
      l_r[r] = l_r[r] * corr[r] + rs;
    }
    #pragma unroll
    for (int ct = 0; ct < 4; ct++)
      #pragma unroll
      for (int r = 0; r < 4; r++)
        sP[wv][(g * 4 + r) * KPAD + ct * 16 + cc] = f2bf(sc[ct][r]);
    #pragma unroll
    for (int dt = 0; dt < 4; dt++)
      #pragma unroll
      for (int r = 0; r < 4; r++)
        accO[dt][r] *= corr[r];
    short8v pf0 = *(const short8v*)(&sP[wv][cc * KPAD + g * 8]);
    short8v pf1 = *(const short8v*)(&sP[wv][cc * KPAD + g * 8 + 32]);
    #pragma unroll
    for (int dt = 0; dt < 4; dt++) {
      short8v v0 = *(const short8v*)(&sVt[(dt * 16 + cc) * KPAD + g * 8]);
      short8v v1 = *(const short8v*)(&sVt[(dt * 16 + cc) * KPAD + g * 8 + 32]);
      accO[dt] = __builtin_amdgcn_mfma_f32_16x16x32_bf16(pf0, v0, accO[dt], 0, 0, 0);
      accO[dt] = __builtin_amdgcn_mfma_f32_16x16x32_bf16(pf1, v1, accO[dt], 0, 0, 0);
    }
    __syncthreads();
  }
  #pragma unroll
  for (int dt = 0; dt < 4; dt++)
    #pragma unroll
    for (int r = 0; r < 4; r++) {
      int q = q0 + wv * 16 + g * 4 + r;
      obf[((size_t)(b * S_ + q)) * 2048 + h * 64 + dt * 16 + cc] = f2bf(accO[dt][r] / l_r[r]);
    }
}

// ---------------- launch ----------------
extern "C" void kernel_launch(void* const* d_in, const int* in_sizes, int n_in,
                              void* d_out, int out_size, void* d_ws, size_t ws_size,
                              hipStream_t stream) {
  const int*   ids   = (const int*)d_in[0];
  const int*   pos   = (const int*)d_in[1];
  const float* embed = (const float*)d_in[2];
  const float* w_qkv = (const float*)d_in[3];
  const float* w_o   = (const float*)d_in[4];
  const float* w_gu  = (const float*)d_in[5];
  const float* w_dn  = (const float*)d_in[6];
  const float* ln1   = (const float*)d_in[7];
  const float* ln2   = (const float*)d_in[8];
  const float* normw = (const float*)d_in[9];
  float* out = (float*)d_out;

  char* p = (char*)d_ws;
  short* wT    = (short*)p; p += (size_t)11264 * 2048 * 2;
  float* h     = (float*)p; p += (size_t)T_ * D_ * 4;
  float* res   = (float*)p; p += (size_t)T_ * D_ * 4;
  short* hnbf  = (short*)p; p += (size_t)T_ * D_ * 2;
  short* obf   = (short*)p; p += (size_t)T_ * D_ * 2;
  short* mlpbf = (short*)p; p += (size_t)T_ * I_ * 2;
  float* tab   = (float*)p; p += (size_t)T_ * 64 * 4;
  short* qbf   = (short*)p; p += (size_t)B_ * HQ_ * S_ * HD_ * 2;
  short* kbf   = (short*)p; p += (size_t)B_ * HKV_ * S_ * HD_ * 2;
  short* vbf   = (short*)p; p += (size_t)B_ * HKV_ * S_ * HD_ * 2;
  short* vtbf  = (short*)p; p += (size_t)B_ * HKV_ * HD_ * S_ * 2;

  dim3 tb(32, 8);
  embed_gather<<<T_ * D_ / 4 / 256, 256, 0, stream>>>(ids, embed, h);
  rope_table<<<T_ * 32 / 256, 256, 0, stream>>>(pos, tab);

  for (int l = 0; l < L_; l++) {
    rmsnorm_add<<<T_, 256, 0, stream>>>(h, res, ln1 + l * D_, hnbf, l == 0 ? 1 : 0, 1);

    transpose_bf16<<<dim3(3072 / 32, 2048 / 32), tb, 0, stream>>>(
        w_qkv + (size_t)l * 2048 * 3072, wT, 2048, 3072);
    gemm_qkv_rope<<<dim3(3072 / BN, T_ / BM), 256, 0, stream>>>(
        hnbf, wT, tab, qbf, kbf, vbf, 2048);

    transpose_v<<<dim3(16, 8, 2), 256, 0, stream>>>(vbf, vtbf);
    attn_mfma<<<dim3(16, 32, 2), 256, 0, stream>>>(qbf, kbf, vtbf, obf);

    transpose_bf16<<<dim3(2048 / 32, 2048 / 32), tb, 0, stream>>>(
        w_o + (size_t)l * 2048 * 2048, wT, 2048, 2048);
    gemm_n64<<<dim3(2048 / 64, T_ / BM), 256, 0, stream>>>(
        obf, wT, h, T_, 2048, 2048);

    rmsnorm_add<<<T_, 256, 0, stream>>>(h, res, ln2 + l * D_, hnbf, 0, 1);

    transpose_bf16<<<dim3(11264 / 32, 2048 / 32), tb, 0, stream>>>(
        w_gu + (size_t)l * 2048 * 11264, wT, 2048, 11264);
    gemm_glu<<<dim3(I_ / 64, T_ / BM), 256, 0, stream>>>(
        hnbf, wT, mlpbf, 2048);

    transpose_bf16<<<dim3(2048 / 32, 5632 / 32), tb, 0, stream>>>(
        w_dn + (size_t)l * 5632 * 2048, wT, 5632, 2048);
    gemm_n64<<<dim3(2048 / 64, T_ / BM), 256, 0, stream>>>(
        mlpbf, wT, h, T_, 2048, 5632);
  }
  rmsnorm_add<<<T_, 256, 0, stream>>>(h, res, normw, out, 0, 0);
}